// Round 9
// baseline (60.215 us; speedup 1.0000x reference)
//
#include <hip/hip_runtime.h>

#define OUT_COLS 448
#define OUT_STRIDE (OUT_COLS * 32)   // 14336 floats per batch row
#define NTREES 128
#define TDEPTH 6
#define NT (NTREES * TDEPTH)         // 768 rows per layer
#define DD 32
#define BB 64
#define PADW 64                      // padded compacted width for fs output

// DPP mov helper (compile-time ctrl)
template <int CTRL, int RMASK = 0xf, bool BC = true>
__device__ __forceinline__ float dppf(float v) {
    return __int_as_float(
        __builtin_amdgcn_update_dpp(0, __float_as_int(v), CTRL, RMASK, 0xf, BC));
}

// full-wave (64-lane) sum, result broadcast to all lanes via readlane
__device__ __forceinline__ float wred64(float x) {
    x += dppf<0x111>(x);
    x += dppf<0x112>(x);
    x += dppf<0x114>(x);
    x += dppf<0x118>(x);
    x += __int_as_float(__builtin_amdgcn_update_dpp(0, __float_as_int(x), 0x142, 0xa, 0xf, false)); // row_bcast15
    x += __int_as_float(__builtin_amdgcn_update_dpp(0, __float_as_int(x), 0x143, 0xc, 0xf, false)); // row_bcast31
    return __int_as_float(__builtin_amdgcn_readlane(__float_as_int(x), 63));
}

// ---------------------------------------------------------------- fs sparsemax via Michelot (one wave/row)
template <int J>
__device__ __forceinline__ void fs_row(const float* __restrict__ zr, int lane,
                                       int* __restrict__ fj, float* __restrict__ fv,
                                       int* __restrict__ fcnt_p) {
    constexpr int T = J / 64;
    float z[T];
    #pragma unroll
    for (int t = 0; t < T; ++t) z[t] = zr[t * 64 + lane];
    float sp = 0.f;
    #pragma unroll
    for (int t = 0; t < T; ++t) sp += z[t];
    float k = (float)J;
    float tau = (wred64(sp) - 1.f) / k;
    #pragma unroll 1
    for (int it = 0; it < 64; ++it) {
        float s2 = 0.f, c2 = 0.f;
        #pragma unroll
        for (int t = 0; t < T; ++t) {
            bool g = z[t] > tau;
            s2 += g ? z[t] : 0.f;
            c2 += g ? 1.f : 0.f;
        }
        float S2 = wred64(s2);
        float K2 = wred64(c2);
        if (K2 == k) break;
        k = K2;
        tau = (S2 - 1.f) / K2;
    }
    unsigned long long below = (1ull << lane) - 1ull;
    int base = 0;
    #pragma unroll
    for (int t = 0; t < T; ++t) {
        bool sup = z[t] > tau;
        unsigned long long m = __ballot(sup);
        int pos = base + __popcll(m & below);
        if (sup && pos < PADW) { fj[pos] = t * 64 + lane; fv[pos] = z[t] - tau; }
        base += __popcll(m);
    }
    int cnt = base < PADW ? base : PADW;
    for (int i = cnt + lane; i < PADW; i += 64) { fj[i] = 0; fv[i] = 0.f; }
    if (lane == 0) *fcnt_p = cnt;
}

// butterfly exchange step S (xor 1<<S within 32 lanes) for es transpose-reduce
template <int S>
__device__ __forceinline__ void bstep(float* a, int lane) {
    constexpr int half = 16 >> S;
    bool up = ((lane >> S) & 1) != 0;
    #pragma unroll
    for (int q = 0; q < half; ++q) {
        float send = up ? a[q] : a[half + q];
        float recv;
        if constexpr (S == 0)      recv = dppf<0xB1>(send);
        else if constexpr (S == 1) recv = dppf<0x4E>(send);
        else recv = __int_as_float(__builtin_amdgcn_ds_swizzle(
                        __float_as_int(send), ((1 << S) << 10) | 0x1F));
        float keep = up ? a[half + q] : a[q];
        a[q] = keep + recv;
    }
}

// ---------------------------------------------------------------- fused prep: copy_x + fs + es
__global__ __launch_bounds__(256)
void prep_kernel(const float* __restrict__ x,
                 const float* __restrict__ f0, const float* __restrict__ f1,
                 const float* __restrict__ f2,
                 const float* __restrict__ e0, const float* __restrict__ e1,
                 const float* __restrict__ e2,
                 int* __restrict__ fjp, float* __restrict__ fvp, int* __restrict__ fcnt,
                 float* __restrict__ part, float* __restrict__ out) {
    int w = blockIdx.x * 4 + (threadIdx.x >> 6);
    int lane = threadIdx.x & 63;

    if (w < 512) {                       // ---- copy x ----
        const float4* x4 = (const float4*)x;
        float4* o4 = (float4*)out;
        int g = w * 64 + lane;
        int b = g >> 9, r = g & 511;
        o4[(size_t)b * (OUT_STRIDE / 4) + r] = x4[g];
        return;
    }
    w -= 512;
    if (w < 3 * NT) {                    // ---- fs ----
        if (w < NT) {
            fs_row<64>(f0 + (size_t)w * 64, lane,
                       fjp + (size_t)w * PADW, fvp + (size_t)w * PADW, fcnt + w);
        } else if (w < 2 * NT) {
            int r = w - NT;
            fs_row<192>(f1 + (size_t)r * 192, lane,
                        fjp + (size_t)(NT + r) * PADW, fvp + (size_t)(NT + r) * PADW,
                        fcnt + NT + r);
        } else {
            int r = w - 2 * NT;
            fs_row<320>(f2 + (size_t)r * 320, lane,
                        fjp + (size_t)(2 * NT + r) * PADW, fvp + (size_t)(2 * NT + r) * PADW,
                        fcnt + 2 * NT + r);
        }
        return;
    }
    w -= 3 * NT;                         // ---- es: w in [0, 6912) ----
    const float* esl; int row, chunk, J; size_t grow;
    if (w < NT)          { esl = e0; row = w; chunk = 0; J = 64; grow = (size_t)row; }
    else if (w < 4 * NT) { int q = w - NT; esl = e1; row = q / 3; chunk = q - row * 3; J = 192; grow = (size_t)(NT + row); }
    else                 { int q = w - 4 * NT; esl = e2; row = q / 5; chunk = q - row * 5; J = 320; grow = (size_t)(2 * NT + row); }

    const float4* zp4 = (const float4*)(esl + ((size_t)row * J + chunk * 64 + lane) * 32);
    float z[32];
    #pragma unroll
    for (int i = 0; i < 8; ++i) {
        float4 v = zp4[i];
        z[4 * i] = v.x; z[4 * i + 1] = v.y; z[4 * i + 2] = v.z; z[4 * i + 3] = v.w;
    }
    float mx = z[0];
    #pragma unroll
    for (int i = 1; i < 32; ++i) mx = fmaxf(mx, z[i]);
    float tau = mx - 1.0f;               // warm start (valid lower bound on tau*)
    int kprev = -1;
    #pragma unroll 1
    for (int it = 0; it < 40; ++it) {
        float s0 = 0.f, s1 = 0.f, s2 = 0.f, s3 = 0.f;
        int k0 = 0, k1 = 0, k2 = 0, k3 = 0;
        #pragma unroll
        for (int i = 0; i < 8; ++i) {
            bool g0 = z[4 * i]     > tau; s0 += g0 ? z[4 * i]     : 0.f; k0 += g0;
            bool g1 = z[4 * i + 1] > tau; s1 += g1 ? z[4 * i + 1] : 0.f; k1 += g1;
            bool g2 = z[4 * i + 2] > tau; s2 += g2 ? z[4 * i + 2] : 0.f; k2 += g2;
            bool g3 = z[4 * i + 3] > tau; s3 += g3 ? z[4 * i + 3] : 0.f; k3 += g3;
        }
        float S = (s0 + s1) + (s2 + s3);
        int k = (k0 + k1) + (k2 + k3);
        bool chg = (k != kprev);
        kprev = k;
        tau = (S - 1.0f) / (float)k;
        if (__ballot(chg) == 0ull) break;
    }
    #pragma unroll
    for (int i = 0; i < 32; ++i) z[i] = fmaxf(z[i] - tau, 0.f);
    bstep<0>(z, lane);
    bstep<1>(z, lane);
    bstep<2>(z, lane);
    bstep<3>(z, lane);
    bstep<4>(z, lane);
    z[0] += __shfl_xor(z[0], 32, 64);
    if (lane < 32) {
        int d = ((lane & 1) << 4) | ((lane & 2) << 2) | (lane & 4)
              | ((lane & 8) >> 2) | ((lane & 16) >> 4);
        part[(grow * 5 + chunk) * 32 + d] = z[0];
    }
}

// ---------------------------------------------------------------- main: thread = (b,d), block = (n, 8 b's)
// Gather rounds interleave ALL SIX trees (48 independent loads in flight per round).
__global__ __launch_bounds__(256)
void main_kernel(const int* __restrict__ fjp, const float* __restrict__ fvp,
                 const int* __restrict__ fcnt, const float* __restrict__ partL, int nch,
                 const float* __restrict__ thr, const float* __restrict__ lt,
                 const float* __restrict__ resp,
                 float* __restrict__ out, int colOff) {
    int n = blockIdx.x;
    int tid = threadIdx.x;
    __shared__ int   s_j[TDEPTH][PADW];
    __shared__ float s_v[TDEPTH][PADW];
    __shared__ float s_resp[DD][65];     // stride 65: bank = (d+c)%32, conflict-free
    __shared__ float s_ess[TDEPTH][DD];
    __shared__ float s_thr[TDEPTH], s_elt[TDEPTH];
    __shared__ int   s_cnt[TDEPTH];

    for (int i = tid; i < TDEPTH * PADW; i += 256) {
        int t = i >> 6, p = i & 63;
        size_t g = (size_t)(n * TDEPTH + t) * PADW + p;
        s_j[t][p] = fjp[g];
        s_v[t][p] = fvp[g];
    }
    for (int i = tid; i < DD * 64; i += 256) {
        s_resp[i >> 6][i & 63] = resp[(size_t)n * (DD * 64) + i];
    }
    if (tid < TDEPTH * DD) {             // 192 threads: ess chunk-sum (deterministic)
        int t = tid >> 5, d = tid & 31;
        float e = 0.f;
        #pragma unroll
        for (int c = 0; c < 5; ++c)
            if (c < nch) e += partL[((size_t)(n * TDEPTH + t) * 5 + c) * 32 + d];
        s_ess[t][d] = e;
    }
    if (tid < TDEPTH) {
        int r = n * TDEPTH + tid;
        s_thr[tid] = thr[r];
        s_elt[tid] = expf(-lt[r]);
        s_cnt[tid] = fcnt[r];
    }
    __syncthreads();

    int b = blockIdx.y * 8 + (tid >> 5);   // 0..63
    int d = tid & 31;
    const float* xb = out + (size_t)b * OUT_STRIDE;

    // block-uniform max count over trees (zero-padded slots make over-read safe)
    int maxc = s_cnt[0];
    #pragma unroll
    for (int t = 1; t < TDEPTH; ++t) maxc = max(maxc, s_cnt[t]);
    int rounds = (maxc + 7) >> 3;

    float acc0 = 0.f, acc1 = 0.f, acc2 = 0.f, acc3 = 0.f, acc4 = 0.f, acc5 = 0.f;
    for (int r = 0; r < rounds; ++r) {
        int p = r * 8;
        float xv[TDEPTH][8];
        #pragma unroll
        for (int t = 0; t < TDEPTH; ++t) {
            #pragma unroll
            for (int q = 0; q < 8; ++q)
                xv[t][q] = xb[s_j[t][p + q] * 32 + d] * s_v[t][p + q];
        }
        #pragma unroll
        for (int t = 0; t < TDEPTH; ++t) {
            float a = ((xv[t][0] + xv[t][1]) + (xv[t][2] + xv[t][3]))
                    + ((xv[t][4] + xv[t][5]) + (xv[t][6] + xv[t][7]));
            if (t == 0) acc0 += a;
            if (t == 1) acc1 += a;
            if (t == 2) acc2 += a;
            if (t == 3) acc3 += a;
            if (t == 4) acc4 += a;
            if (t == 5) acc5 += a;
        }
    }
    float sv[TDEPTH];
    {
        float accs[TDEPTH] = {acc0, acc1, acc2, acc3, acc4, acc5};
        #pragma unroll
        for (int t = 0; t < TDEPTH; ++t) {
            float sel = accs[t] * s_ess[t][d];
            float tlv = (sel - s_thr[t]) * s_elt[t];
            sv[t] = fminf(fmaxf(0.5f * tlv + 0.5f, 0.f), 1.f);
        }
    }

    // A[c1]: trees 0-2 (bit i of c1 set => (1-sv[i])); B[c2]: trees 3-5
    float A[8], Bv[8];
    {
        float a0 = sv[0], a1 = 1.f - sv[0];
        float b0 = sv[1], b1 = 1.f - sv[1];
        float c0 = sv[2], c1 = 1.f - sv[2];
        A[0] = a0 * b0 * c0; A[1] = a1 * b0 * c0;
        A[2] = a0 * b1 * c0; A[3] = a1 * b1 * c0;
        A[4] = a0 * b0 * c1; A[5] = a1 * b0 * c1;
        A[6] = a0 * b1 * c1; A[7] = a1 * b1 * c1;
        float d0 = sv[3], d1 = 1.f - sv[3];
        float e0 = sv[4], e1 = 1.f - sv[4];
        float f0 = sv[5], f1 = 1.f - sv[5];
        Bv[0] = d0 * e0 * f0; Bv[1] = d1 * e0 * f0;
        Bv[2] = d0 * e1 * f0; Bv[3] = d1 * e1 * f0;
        Bv[4] = d0 * e0 * f1; Bv[5] = d1 * e0 * f1;
        Bv[6] = d0 * e1 * f1; Bv[7] = d1 * e1 * f1;
    }
    float o = 0.f;
    #pragma unroll
    for (int c2 = 0; c2 < 8; ++c2) {
        float inner = 0.f;
        #pragma unroll
        for (int c1 = 0; c1 < 8; ++c1)
            inner += A[c1] * s_resp[d][c1 + 8 * c2];
        o += Bv[c2] * inner;
    }
    out[(size_t)b * OUT_STRIDE + (size_t)(colOff + n) * DD + d] = o;
}

// ----------------------------------------------------------------
extern "C" void kernel_launch(void* const* d_in, const int* in_sizes, int n_in,
                              void* d_out, int out_size, void* d_ws, size_t ws_size,
                              hipStream_t stream) {
    const float* x = (const float*)d_in[0];
    float* out = (float*)d_out;

    const size_t NPAD = (size_t)3 * NT * PADW;   // 147456
    char* ws = (char*)d_ws;
    int*   fjp  = (int*)(ws);
    float* fvp  = (float*)(ws + NPAD * 4);
    int*   fcnt = (int*)(ws + 2 * NPAD * 4);
    float* part = (float*)(ws + 2 * NPAD * 4 + 16384);   // [3*NT][5][32]

    // 512 copy + 2304 fs + 6912 es = 9728 wave-tasks, 4 waves/block
    prep_kernel<<<9728 / 4, 256, 0, stream>>>(
        x,
        (const float*)d_in[1], (const float*)d_in[6], (const float*)d_in[11],
        (const float*)d_in[2], (const float*)d_in[7], (const float*)d_in[12],
        fjp, fvp, fcnt, part, out);

    const int nchs[3] = {1, 3, 5};
    int colOff = 64;
    for (int L = 0; L < 3; ++L) {
        const float* thr  = (const float*)d_in[3 + 5 * L];
        const float* lt   = (const float*)d_in[4 + 5 * L];
        const float* resp = (const float*)d_in[5 + 5 * L];
        main_kernel<<<dim3(NTREES, 8), 256, 0, stream>>>(
            fjp + (size_t)L * NT * PADW, fvp + (size_t)L * NT * PADW,
            fcnt + L * NT, part + (size_t)L * NT * 5 * 32, nchs[L],
            thr, lt, resp, out, colOff);
        colOff += NTREES;
    }
}

// Round 10
// 57.825 us; speedup vs baseline: 1.0413x; 1.0413x over previous
//
#include <hip/hip_runtime.h>

#define OUT_COLS 448
#define OUT_STRIDE (OUT_COLS * 32)   // 14336 floats per batch row
#define NTREES 128
#define TDEPTH 6
#define NT (NTREES * TDEPTH)         // 768 rows per layer
#define DD 32
#define BB 64
#define PADW 64                      // padded compacted width for fs output

// DPP mov helper (compile-time ctrl)
template <int CTRL, int RMASK = 0xf, bool BC = true>
__device__ __forceinline__ float dppf(float v) {
    return __int_as_float(
        __builtin_amdgcn_update_dpp(0, __float_as_int(v), CTRL, RMASK, 0xf, BC));
}

// full-wave (64-lane) sum, result broadcast to all lanes via readlane
__device__ __forceinline__ float wred64(float x) {
    x += dppf<0x111>(x);
    x += dppf<0x112>(x);
    x += dppf<0x114>(x);
    x += dppf<0x118>(x);
    x += __int_as_float(__builtin_amdgcn_update_dpp(0, __float_as_int(x), 0x142, 0xa, 0xf, false)); // row_bcast15
    x += __int_as_float(__builtin_amdgcn_update_dpp(0, __float_as_int(x), 0x143, 0xc, 0xf, false)); // row_bcast31
    return __int_as_float(__builtin_amdgcn_readlane(__float_as_int(x), 63));
}

// ---------------------------------------------------------------- fs sparsemax via Michelot (one wave/row)
// Output: interleaved (byte-offset, value) float2 pairs, zero-padded to PADW.
template <int J>
__device__ __forceinline__ void fs_row(const float* __restrict__ zr, int lane,
                                       float2* __restrict__ fjv, int* __restrict__ fcnt_p) {
    constexpr int T = J / 64;
    float z[T];
    #pragma unroll
    for (int t = 0; t < T; ++t) z[t] = zr[t * 64 + lane];
    float sp = 0.f;
    #pragma unroll
    for (int t = 0; t < T; ++t) sp += z[t];
    float k = (float)J;
    float tau = (wred64(sp) - 1.f) / k;
    #pragma unroll 1
    for (int it = 0; it < 64; ++it) {
        float s2 = 0.f, c2 = 0.f;
        #pragma unroll
        for (int t = 0; t < T; ++t) {
            bool g = z[t] > tau;
            s2 += g ? z[t] : 0.f;
            c2 += g ? 1.f : 0.f;
        }
        float S2 = wred64(s2);
        float K2 = wred64(c2);
        if (K2 == k) break;
        k = K2;
        tau = (S2 - 1.f) / K2;
    }
    unsigned long long below = (1ull << lane) - 1ull;
    int base = 0;
    #pragma unroll
    for (int t = 0; t < T; ++t) {
        bool sup = z[t] > tau;
        unsigned long long m = __ballot(sup);
        int pos = base + __popcll(m & below);
        if (sup && pos < PADW)
            fjv[pos] = make_float2(__int_as_float((t * 64 + lane) * 128), z[t] - tau);
        base += __popcll(m);
    }
    int cnt = base < PADW ? base : PADW;
    for (int i = cnt + lane; i < PADW; i += 64)
        fjv[i] = make_float2(__int_as_float(0), 0.f);
    if (lane == 0) *fcnt_p = cnt;
}

// butterfly exchange step S (xor 1<<S within 32 lanes) for es transpose-reduce
template <int S>
__device__ __forceinline__ void bstep(float* a, int lane) {
    constexpr int half = 16 >> S;
    bool up = ((lane >> S) & 1) != 0;
    #pragma unroll
    for (int q = 0; q < half; ++q) {
        float send = up ? a[q] : a[half + q];
        float recv;
        if constexpr (S == 0)      recv = dppf<0xB1>(send);
        else if constexpr (S == 1) recv = dppf<0x4E>(send);
        else recv = __int_as_float(__builtin_amdgcn_ds_swizzle(
                        __float_as_int(send), ((1 << S) << 10) | 0x1F));
        float keep = up ? a[half + q] : a[q];
        a[q] = keep + recv;
    }
}

// ---------------------------------------------------------------- fused prep: copy_x + fs + es
__global__ __launch_bounds__(256)
void prep_kernel(const float* __restrict__ x,
                 const float* __restrict__ f0, const float* __restrict__ f1,
                 const float* __restrict__ f2,
                 const float* __restrict__ e0, const float* __restrict__ e1,
                 const float* __restrict__ e2,
                 float2* __restrict__ fjv, int* __restrict__ fcnt,
                 float* __restrict__ part, float* __restrict__ out) {
    int w = blockIdx.x * 4 + (threadIdx.x >> 6);
    int lane = threadIdx.x & 63;

    if (w < 512) {                       // ---- copy x ----
        const float4* x4 = (const float4*)x;
        float4* o4 = (float4*)out;
        int g = w * 64 + lane;
        int b = g >> 9, r = g & 511;
        o4[(size_t)b * (OUT_STRIDE / 4) + r] = x4[g];
        return;
    }
    w -= 512;
    if (w < 3 * NT) {                    // ---- fs ----
        if (w < NT) {
            fs_row<64>(f0 + (size_t)w * 64, lane, fjv + (size_t)w * PADW, fcnt + w);
        } else if (w < 2 * NT) {
            int r = w - NT;
            fs_row<192>(f1 + (size_t)r * 192, lane,
                        fjv + (size_t)(NT + r) * PADW, fcnt + NT + r);
        } else {
            int r = w - 2 * NT;
            fs_row<320>(f2 + (size_t)r * 320, lane,
                        fjv + (size_t)(2 * NT + r) * PADW, fcnt + 2 * NT + r);
        }
        return;
    }
    w -= 3 * NT;                         // ---- es: w in [0, 6912) ----
    const float* esl; int row, chunk, J; size_t grow;
    if (w < NT)          { esl = e0; row = w; chunk = 0; J = 64; grow = (size_t)row; }
    else if (w < 4 * NT) { int q = w - NT; esl = e1; row = q / 3; chunk = q - row * 3; J = 192; grow = (size_t)(NT + row); }
    else                 { int q = w - 4 * NT; esl = e2; row = q / 5; chunk = q - row * 5; J = 320; grow = (size_t)(2 * NT + row); }

    const float4* zp4 = (const float4*)(esl + ((size_t)row * J + chunk * 64 + lane) * 32);
    float z[32];
    #pragma unroll
    for (int i = 0; i < 8; ++i) {
        float4 v = zp4[i];
        z[4 * i] = v.x; z[4 * i + 1] = v.y; z[4 * i + 2] = v.z; z[4 * i + 3] = v.w;
    }
    float mx = z[0];
    #pragma unroll
    for (int i = 1; i < 32; ++i) mx = fmaxf(mx, z[i]);
    float tau = mx - 1.0f;               // warm start (valid lower bound on tau*)
    int kprev = -1;
    #pragma unroll 1
    for (int it = 0; it < 40; ++it) {
        float s0 = 0.f, s1 = 0.f, s2 = 0.f, s3 = 0.f;
        int k0 = 0, k1 = 0, k2 = 0, k3 = 0;
        #pragma unroll
        for (int i = 0; i < 8; ++i) {
            bool g0 = z[4 * i]     > tau; s0 += g0 ? z[4 * i]     : 0.f; k0 += g0;
            bool g1 = z[4 * i + 1] > tau; s1 += g1 ? z[4 * i + 1] : 0.f; k1 += g1;
            bool g2 = z[4 * i + 2] > tau; s2 += g2 ? z[4 * i + 2] : 0.f; k2 += g2;
            bool g3 = z[4 * i + 3] > tau; s3 += g3 ? z[4 * i + 3] : 0.f; k3 += g3;
        }
        float S = (s0 + s1) + (s2 + s3);
        int k = (k0 + k1) + (k2 + k3);
        bool chg = (k != kprev);
        kprev = k;
        tau = (S - 1.0f) / (float)k;
        if (__ballot(chg) == 0ull) break;
    }
    #pragma unroll
    for (int i = 0; i < 32; ++i) z[i] = fmaxf(z[i] - tau, 0.f);
    bstep<0>(z, lane);
    bstep<1>(z, lane);
    bstep<2>(z, lane);
    bstep<3>(z, lane);
    bstep<4>(z, lane);
    z[0] += __shfl_xor(z[0], 32, 64);
    if (lane < 32) {
        int d = ((lane & 1) << 4) | ((lane & 2) << 2) | (lane & 4)
              | ((lane & 8) >> 2) | ((lane & 16) >> 4);
        part[(grow * 5 + chunk) * 32 + d] = z[0];
    }
}

// ---------------------------------------------------------------- main: thread = (b,d), block = (n, 8 b's)
// (j,v) pairs packed in LDS float4 (2 pairs per ds_read_b128); resp dot via float2, stride 66.
__global__ __launch_bounds__(256)
void main_kernel(const float2* __restrict__ fjvL, const int* __restrict__ fcnt,
                 const float* __restrict__ partL, int nch,
                 const float* __restrict__ thr, const float* __restrict__ lt,
                 const float* __restrict__ resp,
                 float* __restrict__ out, int colOff) {
    int n = blockIdx.x;
    int tid = threadIdx.x;
    __shared__ float4 s_jv[TDEPTH][PADW / 2];   // (joff,v,joff,v) x 32 per tree
    __shared__ float2 s_resp2[DD][33];          // row stride 66 floats: 2-way alias only
    __shared__ float  s_ess[TDEPTH][DD];
    __shared__ float  s_thr[TDEPTH], s_elt[TDEPTH];
    __shared__ int    s_cnt[TDEPTH];

    {   // stage jv: 192 contiguous float4 for rows n*6..n*6+5
        const float4* g = (const float4*)(fjvL + (size_t)n * TDEPTH * PADW);
        if (tid < 192) ((float4*)s_jv)[tid] = g[tid];
    }
    {   // stage resp: 1024 float2
        const float2* g = (const float2*)(resp + (size_t)n * (DD * 64));
        for (int i = tid; i < DD * 32; i += 256)
            s_resp2[i >> 5][i & 31] = g[i];
    }
    if (tid < TDEPTH * DD) {             // 192 threads: ess chunk-sum (deterministic)
        int t = tid >> 5, d = tid & 31;
        float e = 0.f;
        #pragma unroll
        for (int c = 0; c < 5; ++c)
            if (c < nch) e += partL[((size_t)(n * TDEPTH + t) * 5 + c) * 32 + d];
        s_ess[t][d] = e;
    }
    if (tid < TDEPTH) {
        int r = n * TDEPTH + tid;
        s_thr[tid] = thr[r];
        s_elt[tid] = expf(-lt[r]);
        s_cnt[tid] = fcnt[r];
    }
    __syncthreads();

    int b = blockIdx.y * 8 + (tid >> 5);   // 0..63
    int d = tid & 31;
    const char* xbd = (const char*)(out + (size_t)b * OUT_STRIDE + d);  // +joff bytes = x[b][j][d]

    int maxc = s_cnt[0];
    #pragma unroll
    for (int t = 1; t < TDEPTH; ++t) maxc = max(maxc, s_cnt[t]);
    int rounds = (maxc + 7) >> 3;          // 8 pairs (4 float4) per tree per round

    float acc0 = 0.f, acc1 = 0.f, acc2 = 0.f, acc3 = 0.f, acc4 = 0.f, acc5 = 0.f;
    for (int r = 0; r < rounds; ++r) {
        int p4 = r * 4;
        #pragma unroll
        for (int t = 0; t < TDEPTH; ++t) {
            float4 q0 = s_jv[t][p4 + 0];
            float4 q1 = s_jv[t][p4 + 1];
            float4 q2 = s_jv[t][p4 + 2];
            float4 q3 = s_jv[t][p4 + 3];
            float x0 = *(const float*)(xbd + __float_as_int(q0.x));
            float x1 = *(const float*)(xbd + __float_as_int(q0.z));
            float x2 = *(const float*)(xbd + __float_as_int(q1.x));
            float x3 = *(const float*)(xbd + __float_as_int(q1.z));
            float x4 = *(const float*)(xbd + __float_as_int(q2.x));
            float x5 = *(const float*)(xbd + __float_as_int(q2.z));
            float x6 = *(const float*)(xbd + __float_as_int(q3.x));
            float x7 = *(const float*)(xbd + __float_as_int(q3.z));
            float a = ((x0 * q0.y + x1 * q0.w) + (x2 * q1.y + x3 * q1.w))
                    + ((x4 * q2.y + x5 * q2.w) + (x6 * q3.y + x7 * q3.w));
            if (t == 0) acc0 += a;
            if (t == 1) acc1 += a;
            if (t == 2) acc2 += a;
            if (t == 3) acc3 += a;
            if (t == 4) acc4 += a;
            if (t == 5) acc5 += a;
        }
    }
    float sv[TDEPTH];
    {
        float accs[TDEPTH] = {acc0, acc1, acc2, acc3, acc4, acc5};
        #pragma unroll
        for (int t = 0; t < TDEPTH; ++t) {
            float sel = accs[t] * s_ess[t][d];
            float tlv = (sel - s_thr[t]) * s_elt[t];
            sv[t] = fminf(fmaxf(0.5f * tlv + 0.5f, 0.f), 1.f);
        }
    }

    // A[c1]: trees 0-2 (bit i of c1 set => (1-sv[i])); B[c2]: trees 3-5
    float A[8], Bv[8];
    {
        float a0 = sv[0], a1 = 1.f - sv[0];
        float b0 = sv[1], b1 = 1.f - sv[1];
        float c0 = sv[2], c1 = 1.f - sv[2];
        A[0] = a0 * b0 * c0; A[1] = a1 * b0 * c0;
        A[2] = a0 * b1 * c0; A[3] = a1 * b1 * c0;
        A[4] = a0 * b0 * c1; A[5] = a1 * b0 * c1;
        A[6] = a0 * b1 * c1; A[7] = a1 * b1 * c1;
        float d0 = sv[3], d1 = 1.f - sv[3];
        float e0 = sv[4], e1 = 1.f - sv[4];
        float f0 = sv[5], f1 = 1.f - sv[5];
        Bv[0] = d0 * e0 * f0; Bv[1] = d1 * e0 * f0;
        Bv[2] = d0 * e1 * f0; Bv[3] = d1 * e1 * f0;
        Bv[4] = d0 * e0 * f1; Bv[5] = d1 * e0 * f1;
        Bv[6] = d0 * e1 * f1; Bv[7] = d1 * e1 * f1;
    }
    float o = 0.f;
    #pragma unroll
    for (int c2 = 0; c2 < 8; ++c2) {
        float2 r0 = s_resp2[d][(8 * c2) >> 1];
        float2 r1 = s_resp2[d][(8 * c2 + 2) >> 1];
        float2 r2 = s_resp2[d][(8 * c2 + 4) >> 1];
        float2 r3 = s_resp2[d][(8 * c2 + 6) >> 1];
        float inner = (A[0] * r0.x + A[1] * r0.y) + (A[2] * r1.x + A[3] * r1.y)
                    + (A[4] * r2.x + A[5] * r2.y) + (A[6] * r3.x + A[7] * r3.y);
        o += Bv[c2] * inner;
    }
    out[(size_t)b * OUT_STRIDE + (size_t)(colOff + n) * DD + d] = o;
}

// ----------------------------------------------------------------
extern "C" void kernel_launch(void* const* d_in, const int* in_sizes, int n_in,
                              void* d_out, int out_size, void* d_ws, size_t ws_size,
                              hipStream_t stream) {
    const float* x = (const float*)d_in[0];
    float* out = (float*)d_out;

    const size_t NPAD = (size_t)3 * NT * PADW;   // 147456 pairs
    char* ws = (char*)d_ws;
    float2* fjv  = (float2*)(ws);                         // 1.18 MB
    int*    fcnt = (int*)(ws + NPAD * 8);
    float*  part = (float*)(ws + NPAD * 8 + 16384);       // [3*NT][5][32]

    // 512 copy + 2304 fs + 6912 es = 9728 wave-tasks, 4 waves/block
    prep_kernel<<<9728 / 4, 256, 0, stream>>>(
        x,
        (const float*)d_in[1], (const float*)d_in[6], (const float*)d_in[11],
        (const float*)d_in[2], (const float*)d_in[7], (const float*)d_in[12],
        fjv, fcnt, part, out);

    const int nchs[3] = {1, 3, 5};
    int colOff = 64;
    for (int L = 0; L < 3; ++L) {
        const float* thr  = (const float*)d_in[3 + 5 * L];
        const float* lt   = (const float*)d_in[4 + 5 * L];
        const float* resp = (const float*)d_in[5 + 5 * L];
        main_kernel<<<dim3(NTREES, 8), 256, 0, stream>>>(
            fjv + (size_t)L * NT * PADW, fcnt + L * NT,
            part + (size_t)L * NT * 5 * 32, nchs[L],
            thr, lt, resp, out, colOff);
        colOff += NTREES;
    }
}